// Round 8
// baseline (878.566 us; speedup 1.0000x reference)
//
#include <hip/hip_runtime.h>
#include <hip/hip_bf16.h>

// Problem constants (from setup_inputs)
#define N_NODES 20000
#define NANG 8
#define CH 64                      // in_size == out_size == 64
#define M_ROWS (NANG * N_NODES)    // 160000
#define E_EDGES (M_ROWS * 16)      // 2560000
#define K_CHEB 8
#define WK_STRIDE (NANG * CH * CH) // 32768 floats per weight[k]
#define BROWS 256                  // rows per bucket (256 -> good scatter write-combining)
#define NB (M_ROWS / BROWS)        // 625 buckets
#define NCHUNK 320
#define CHUNK (E_EDGES / NCHUNK)   // 8000
#define GEMM_BLOCKS 313            // ceil((N_NODES/16)/4)
#define SPMM_BLOCKS (M_ROWS / 4)   // 40000

typedef short short8 __attribute__((ext_vector_type(8)));
typedef float f32x4 __attribute__((ext_vector_type(4)));

__device__ __forceinline__ float bf2f(ushort u) {
    return __uint_as_float((unsigned int)u << 16);
}

// ---------------- deterministic bucket build (no global atomics) ----------------

// per-(chunk,bucket) histogram
__global__ __launch_bounds__(256) void count_kernel(const int* __restrict__ rows,
                                                    int* __restrict__ chunk_cnt) {
    __shared__ int h[NB];
    int c = blockIdx.x, tid = threadIdx.x;
    for (int i = tid; i < NB; i += 256) h[i] = 0;
    __syncthreads();
    int base = c * CHUNK;
    for (int i = tid; i < CHUNK; i += 256) atomicAdd(&h[rows[base + i] >> 8], 1);
    __syncthreads();
    for (int i = tid; i < NB; i += 256) chunk_cnt[(size_t)c * NB + i] = h[i];
}

__global__ void btotal_kernel(const int* __restrict__ chunk_cnt, int* __restrict__ btotal) {
    int b = blockIdx.x * 256 + threadIdx.x;
    if (b >= NB) return;
    int s = 0;
    for (int c = 0; c < NCHUNK; ++c) s += chunk_cnt[(size_t)c * NB + b];
    btotal[b] = s;
}

// single-block exclusive scan over NB bucket totals (1 per thread; NB=625 <= 1024)
__global__ void bscan_kernel(const int* __restrict__ btotal, int* __restrict__ bstart) {
    __shared__ int s[1024];
    int t = threadIdx.x;
    int v = (t < NB) ? btotal[t] : 0;
    s[t] = v;
    __syncthreads();
    for (int off = 1; off < 1024; off <<= 1) {
        int u = (t >= off) ? s[t - off] : 0;
        __syncthreads();
        s[t] += u;
        __syncthreads();
    }
    if (t < NB) bstart[t] = s[t] - v;
    if (t == 1023) bstart[NB] = s[1023];
}

// chunk_cnt -> per-(chunk,bucket) write offsets, in place
__global__ void offs_kernel(int* __restrict__ chunk_cnt, const int* __restrict__ bstart) {
    int b = blockIdx.x * 256 + threadIdx.x;
    if (b >= NB) return;
    int run = bstart[b];
    for (int c = 0; c < NCHUNK; ++c) {
        int v = chunk_cnt[(size_t)c * NB + b];
        chunk_cnt[(size_t)c * NB + b] = run;
        run += v;
    }
}

// scatter into bucket-ordered streams (LDS-local offsets, sequential per-bucket writes)
__global__ __launch_bounds__(256) void scatter_kernel(
        const int* __restrict__ rows, const int* __restrict__ cols,
        const float* __restrict__ vals, const int* __restrict__ chunk_cnt,
        int2* __restrict__ bedges) {
    __shared__ int loff[NB];
    int c = blockIdx.x, tid = threadIdx.x;
    for (int i = tid; i < NB; i += 256) loff[i] = chunk_cnt[(size_t)c * NB + i];
    __syncthreads();
    int base = c * CHUNK;
    for (int i = tid; i < CHUNK; i += 256) {
        int e = base + i;
        int r = rows[e];
        int p = atomicAdd(&loff[r >> 8], 1);
        bedges[p] = make_int2(cols[e] | ((r & 255) << 18), __float_as_int(vals[e]));
    }
}

// per-bucket: group edges by row (no col sort), write to final CSR slots; emit row_start.
__global__ __launch_bounds__(256) void bucket_group_kernel(
        const int* __restrict__ bstart, const int2* __restrict__ bin,
        int2* __restrict__ bout, int* __restrict__ row_start) {
    __shared__ int cnt[BROWS];
    __shared__ int pref[BROWS];
    __shared__ int fill[BROWS];
    int b = blockIdx.x, tid = threadIdx.x;
    int s = bstart[b], e = bstart[b + 1];
    int n = e - s;
    cnt[tid] = 0;
    __syncthreads();
    int2 eds[16];                      // reg cache (n ~ 4096 avg; guarded)
    int ni = 0;
    for (int i = tid; i < n; i += 256, ++ni) {
        int2 ed = bin[s + i];
        if (ni < 16) eds[ni] = ed;
        atomicAdd(&cnt[(ed.x >> 18) & 255], 1);
    }
    __syncthreads();
    if (tid == 0) {
        int run = 0;
#pragma unroll
        for (int r = 0; r < BROWS; ++r) { pref[r] = run; run += cnt[r]; }
    }
    __syncthreads();
    fill[tid] = pref[tid];
    __syncthreads();
    ni = 0;
    for (int i = tid; i < n; i += 256, ++ni) {
        int2 ed = (ni < 16) ? eds[ni] : bin[s + i];
        int p = atomicAdd(&fill[(ed.x >> 18) & 255], 1);
        bout[s + p] = make_int2(ed.x & 0x3ffff, ed.y);
    }
    row_start[b * BROWS + tid] = s + pref[tid];
    if (b == NB - 1 && tid == 0) row_start[M_ROWS] = e;
}

// ---------------- small converts ----------------

__global__ void xconv_kernel(const float* __restrict__ x, ushort* __restrict__ xb) {
    int i = blockIdx.x * 256 + threadIdx.x;
    __hip_bfloat16 v = __float2bfloat16(x[i]);
    xb[i] = *(ushort*)&v;
}

// Wt[k][n][kk] = bf16(W[k][kk][n])
__global__ void wconv_kernel(const float* __restrict__ W, ushort* __restrict__ Wt) {
    int idx = blockIdx.x * 256 + threadIdx.x;
    int kk = idx & 511;
    int n  = (idx >> 9) & 63;
    int k  = idx >> 15;
    __hip_bfloat16 v = __float2bfloat16(W[(size_t)k * WK_STRIDE + kk * 64 + n]);
    Wt[idx] = *(ushort*)&v;
}

// Wsum[n][ck] = bf16( sum_a W[0][a*64+ck][n] )  (tile(x)@W0 == x@Wsum)
__global__ void wsum_kernel(const float* __restrict__ W, ushort* __restrict__ Wsum) {
    int idx = blockIdx.x * 256 + threadIdx.x;
    int ck = idx & 63;
    int n  = idx >> 6;
    float s = 0.f;
#pragma unroll
    for (int a = 0; a < NANG; ++a) s += W[(a * 64 + ck) * 64 + n];
    __hip_bfloat16 v = __float2bfloat16(s);
    Wsum[idx] = *(ushort*)&v;
}

// ---------------- spmm row body (readlane edge broadcast, MLP=16) ----------------

template <int TIN_TILED, int TSUB_MODE>
__device__ __forceinline__ void spmm_row(
        int r, int lane,
        const int* __restrict__ row_start, const int2* __restrict__ edges,
        const ushort* __restrict__ Tin, const ushort* __restrict__ Tsub,
        ushort* __restrict__ Tout, float alpha, float beta) {
    int s = row_start[r];
    int e = row_start[r + 1];
    float acc = 0.f;
    for (int base = s; base < e; base += 16) {
        int idx = min(base + (lane & 15), e - 1);
        int2 ed = edges[idx];                 // 16 edges, 128B coalesced (4x dup)
#pragma unroll
        for (int i = 0; i < 16; ++i) {
            int   col = __builtin_amdgcn_readlane(ed.x, i);
            float w   = __int_as_float(__builtin_amdgcn_readlane(ed.y, i));
            if (base + i >= e) w = 0.f;       // clamped dup edge contributes 0
            unsigned c = (unsigned)col;
            if (TIN_TILED) c %= N_NODES;
            float t = bf2f(Tin[(size_t)c * CH + lane]);
            acc = fmaf(w, t, acc);
        }
    }
    size_t oi = (size_t)r * CH + lane;
    float v = alpha * acc;
    if (TSUB_MODE == 1) v += beta * bf2f(Tsub[oi]);
    if (TSUB_MODE == 2) v += beta * bf2f(Tsub[(size_t)((unsigned)r % N_NODES) * CH + lane]);
    __hip_bfloat16 o = __float2bfloat16(v);
    Tout[oi] = *(ushort*)&o;
}

// ---------------- gemm wave body (MFMA 16x16x32 bf16) ----------------
// C/D layout: col=lane&15, row=(lane>>4)*4+reg  [m89-verified]

template <int KSTEPS, int ACC>
__device__ __forceinline__ void gemm_wave(
        int wave, int l,
        const ushort* __restrict__ T,
        const ushort* __restrict__ Wp,    // [64][KSTEPS*32] bf16
        const float* __restrict__ bias,
        float* __restrict__ out) {        // [N_NODES, 64] fp32
    const int KSTRIDE = KSTEPS * 32;
    int m0 = wave * 16;
    if (m0 >= N_NODES) return;
    int lm = l & 15;
    int lq = l >> 4;

    f32x4 acc[4];
#pragma unroll
    for (int t = 0; t < 4; ++t) acc[t] = (f32x4){0.f, 0.f, 0.f, 0.f};

#pragma unroll
    for (int ks = 0; ks < KSTEPS; ++ks) {
        int a  = ks >> 1;
        int c0 = (ks & 1) * 32;
        short8 af = *(const short8*)(T + ((size_t)(a * N_NODES + m0 + lm)) * CH + c0 + lq * 8);
#pragma unroll
        for (int t = 0; t < 4; ++t) {
            short8 bfrag = *(const short8*)(Wp + (size_t)(t * 16 + lm) * KSTRIDE + ks * 32 + lq * 8);
            acc[t] = __builtin_amdgcn_mfma_f32_16x16x32_bf16(af, bfrag, acc[t], 0, 0, 0);
        }
    }

#pragma unroll
    for (int t = 0; t < 4; ++t) {
        int col = t * 16 + lm;
#pragma unroll
        for (int rI = 0; rI < 4; ++rI) {
            int row = m0 + lq * 4 + rI;
            size_t oi = (size_t)row * CH + col;
            if (ACC) out[oi] += acc[t][rI];
            else     out[oi] = acc[t][rI] + bias[col];
        }
    }
}

// ---------------- fused: gemm_k (313 blocks) + spmm_{k+1} (40000 blocks) ----------------
// No data dependency: both only READ Tg/Tin (completed by the previous dispatch).
// gemm blocks first so MFMA work overlaps the latency-bound spmm from the start.

template <int TIN_TILED, int TSUB_MODE, int KSTEPS, int ACC>
__global__ __launch_bounds__(256) void fused_kernel(
        const int* __restrict__ row_start, const int2* __restrict__ edges,
        const ushort* __restrict__ Tin, const ushort* __restrict__ Tsub,
        ushort* __restrict__ Tout, float alpha, float beta,
        const ushort* __restrict__ Tg, const ushort* __restrict__ Wp,
        const float* __restrict__ bias, float* __restrict__ out) {
    int lane = threadIdx.x & 63;
    if (blockIdx.x < GEMM_BLOCKS) {
        int wave = (blockIdx.x * 256 + threadIdx.x) >> 6;
        gemm_wave<KSTEPS, ACC>(wave, lane, Tg, Wp, bias, out);
    } else {
        int r = ((blockIdx.x - GEMM_BLOCKS) * 256 + threadIdx.x) >> 6;
        if (r < M_ROWS)
            spmm_row<TIN_TILED, TSUB_MODE>(r, lane, row_start, edges, Tin, Tsub, Tout, alpha, beta);
    }
}

// standalone gemm for the last k (no spmm partner)
template <int KSTEPS, int ACC>
__global__ __launch_bounds__(256) void gemm_mfma_kernel(
        const ushort* __restrict__ T, const ushort* __restrict__ Wp,
        const float* __restrict__ bias, float* __restrict__ out) {
    int wave = (blockIdx.x * 256 + threadIdx.x) >> 6;
    gemm_wave<KSTEPS, ACC>(wave, threadIdx.x & 63, T, Wp, bias, out);
}

// ---------------- launch ----------------

extern "C" void kernel_launch(void* const* d_in, const int* in_sizes, int n_in,
                              void* d_out, int out_size, void* d_ws, size_t ws_size,
                              hipStream_t stream) {
    (void)in_sizes; (void)n_in; (void)out_size; (void)ws_size;
    const float* x       = (const float*)d_in[0];
    const float* ls_vals = (const float*)d_in[1];
    const float* weight  = (const float*)d_in[2];
    const float* bias    = (const float*)d_in[3];
    const int*   ls_rows = (const int*)d_in[4];
    const int*   ls_cols = (const int*)d_in[5];
    float* out = (float*)d_out;

    char* ws = (char*)d_ws;
    size_t off = 0;
    auto alloc = [&](size_t bytes) -> void* {
        void* p = ws + off;
        off += (bytes + 255) & ~(size_t)255;
        return p;
    };
    int*  chunk_cnt = (int*)alloc((size_t)NCHUNK * NB * sizeof(int));
    int*  btotal    = (int*)alloc(NB * sizeof(int));
    int*  bstart    = (int*)alloc((NB + 1) * sizeof(int));
    int*  row_start = (int*)alloc((M_ROWS + 1) * sizeof(int));
    int2* bedges    = (int2*)alloc((size_t)E_EDGES * sizeof(int2));
    int2* bedges2   = (int2*)alloc((size_t)E_EDGES * sizeof(int2));
    ushort* Wt   = (ushort*)alloc((size_t)K_CHEB * 64 * 512 * sizeof(ushort));
    ushort* Wsum = (ushort*)alloc(64 * 64 * sizeof(ushort));
    ushort* xb   = (ushort*)alloc((size_t)N_NODES * CH * sizeof(ushort));
    ushort* T1   = (ushort*)alloc((size_t)M_ROWS * CH * sizeof(ushort));
    ushort* T2   = (ushort*)alloc((size_t)M_ROWS * CH * sizeof(ushort));
    ushort* T3   = (ushort*)alloc((size_t)M_ROWS * CH * sizeof(ushort));

    const int fused_blocks = GEMM_BLOCKS + SPMM_BLOCKS;

    // deterministic bucket build + per-bucket row grouping
    count_kernel<<<NCHUNK, 256, 0, stream>>>(ls_rows, chunk_cnt);
    btotal_kernel<<<(NB + 255) / 256, 256, 0, stream>>>(chunk_cnt, btotal);
    bscan_kernel<<<1, 1024, 0, stream>>>(btotal, bstart);
    offs_kernel<<<(NB + 255) / 256, 256, 0, stream>>>(chunk_cnt, bstart);
    scatter_kernel<<<NCHUNK, 256, 0, stream>>>(ls_rows, ls_cols, ls_vals, chunk_cnt, bedges);
    bucket_group_kernel<<<NB, 256, 0, stream>>>(bstart, bedges, bedges2, row_start);

    // converts
    xconv_kernel<<<(N_NODES * CH) / 256, 256, 0, stream>>>(x, xb);
    wconv_kernel<<<(K_CHEB * 64 * 512) / 256, 256, 0, stream>>>(weight, Wt);
    wsum_kernel<<<(64 * 64) / 256, 256, 0, stream>>>(weight, Wsum);

    // F1: gemm0 (out = x@Wsum + bias) + spmm1 (T1 = L tile(x), gathers from xb)
    fused_kernel<1, 0, 2, 0><<<fused_blocks, 256, 0, stream>>>(
        row_start, bedges2, xb, xb, T1, 1.f, 0.f, xb, Wsum, bias, out);

    // F2: gemm1 (T1) + spmm2 (T2 = 2 L T1 - tile(x))
    fused_kernel<0, 2, 16, 1><<<fused_blocks, 256, 0, stream>>>(
        row_start, bedges2, T1, xb, T2, 2.f, -1.f, T1, Wt + (size_t)1 * 64 * 512, bias, out);

    // F3..F7: gemm_{k-1} (Tc) + spmm_k (Tn = 2 L Tc - Tp)
    ushort* Tp = T1;
    ushort* Tc = T2;
    ushort* Tn = T3;
    for (int k = 3; k < K_CHEB; ++k) {
        fused_kernel<0, 1, 16, 1><<<fused_blocks, 256, 0, stream>>>(
            row_start, bedges2, Tc, Tp, Tn, 2.f, -1.f,
            Tc, Wt + (size_t)(k - 1) * 64 * 512, bias, out);
        ushort* t = Tp; Tp = Tc; Tc = Tn; Tn = t;
    }

    // G7: last gemm (T7 = Tc after rotation)
    gemm_mfma_kernel<16, 1><<<GEMM_BLOCKS, 256, 0, stream>>>(
        Tc, Wt + (size_t)7 * 64 * 512, bias, out);
}

// Round 9
// 774.829 us; speedup vs baseline: 1.1339x; 1.1339x over previous
//
#include <hip/hip_runtime.h>
#include <hip/hip_bf16.h>

// Problem constants (from setup_inputs)
#define N_NODES 20000
#define NANG 8
#define CH 64                      // in_size == out_size == 64
#define M_ROWS (NANG * N_NODES)    // 160000
#define E_EDGES (M_ROWS * 16)      // 2560000
#define K_CHEB 8
#define WK_STRIDE (NANG * CH * CH) // 32768 floats per weight[k]
#define BROWS 256                  // rows per bucket (good scatter write-combining)
#define NB (M_ROWS / BROWS)        // 625 buckets
#define NCHUNK 320
#define CHUNK (E_EDGES / NCHUNK)   // 8000
#define SPMM_BLOCKS (M_ROWS / 4)   // 40000
#define KCAT 3648                  // 64 (x@Wsum) + 7*512 (feat(Tk)@Wk)

typedef short short8 __attribute__((ext_vector_type(8)));
typedef float f32x4 __attribute__((ext_vector_type(4)));

__device__ __forceinline__ float bf2f(ushort u) {
    return __uint_as_float((unsigned int)u << 16);
}

// ---------------- deterministic bucket build (no global atomics) ----------------

__global__ __launch_bounds__(256) void count_kernel(const int* __restrict__ rows,
                                                    int* __restrict__ chunk_cnt) {
    __shared__ int h[NB];
    int c = blockIdx.x, tid = threadIdx.x;
    for (int i = tid; i < NB; i += 256) h[i] = 0;
    __syncthreads();
    int base = c * CHUNK;
    for (int i = tid; i < CHUNK; i += 256) atomicAdd(&h[rows[base + i] >> 8], 1);
    __syncthreads();
    for (int i = tid; i < NB; i += 256) chunk_cnt[(size_t)c * NB + i] = h[i];
}

__global__ void btotal_kernel(const int* __restrict__ chunk_cnt, int* __restrict__ btotal) {
    int b = blockIdx.x * 256 + threadIdx.x;
    if (b >= NB) return;
    int s = 0;
    for (int c = 0; c < NCHUNK; ++c) s += chunk_cnt[(size_t)c * NB + b];
    btotal[b] = s;
}

// single-block exclusive scan over NB bucket totals (NB=625 <= 1024)
__global__ void bscan_kernel(const int* __restrict__ btotal, int* __restrict__ bstart) {
    __shared__ int s[1024];
    int t = threadIdx.x;
    int v = (t < NB) ? btotal[t] : 0;
    s[t] = v;
    __syncthreads();
    for (int off = 1; off < 1024; off <<= 1) {
        int u = (t >= off) ? s[t - off] : 0;
        __syncthreads();
        s[t] += u;
        __syncthreads();
    }
    if (t < NB) bstart[t] = s[t] - v;
    if (t == 1023) bstart[NB] = s[1023];
}

// chunk_cnt -> per-(chunk,bucket) write offsets, in place
__global__ void offs_kernel(int* __restrict__ chunk_cnt, const int* __restrict__ bstart) {
    int b = blockIdx.x * 256 + threadIdx.x;
    if (b >= NB) return;
    int run = bstart[b];
    for (int c = 0; c < NCHUNK; ++c) {
        int v = chunk_cnt[(size_t)c * NB + b];
        chunk_cnt[(size_t)c * NB + b] = run;
        run += v;
    }
}

// scatter into bucket-ordered streams (LDS-local offsets, sequential per-bucket writes)
__global__ __launch_bounds__(256) void scatter_kernel(
        const int* __restrict__ rows, const int* __restrict__ cols,
        const float* __restrict__ vals, const int* __restrict__ chunk_cnt,
        int2* __restrict__ bedges) {
    __shared__ int loff[NB];
    int c = blockIdx.x, tid = threadIdx.x;
    for (int i = tid; i < NB; i += 256) loff[i] = chunk_cnt[(size_t)c * NB + i];
    __syncthreads();
    int base = c * CHUNK;
    for (int i = tid; i < CHUNK; i += 256) {
        int e = base + i;
        int r = rows[e];
        int p = atomicAdd(&loff[r >> 8], 1);
        bedges[p] = make_int2(cols[e] | ((r & 255) << 18), __float_as_int(vals[e]));
    }
}

// per-bucket: group edges by row, write to final CSR slots; emit row_start.
__global__ __launch_bounds__(256) void bucket_group_kernel(
        const int* __restrict__ bstart, const int2* __restrict__ bin,
        int2* __restrict__ bout, int* __restrict__ row_start) {
    __shared__ int cnt[BROWS];
    __shared__ int pref[BROWS];
    __shared__ int fill[BROWS];
    int b = blockIdx.x, tid = threadIdx.x;
    int s = bstart[b], e = bstart[b + 1];
    int n = e - s;
    cnt[tid] = 0;
    __syncthreads();
    int2 eds[16];                      // reg cache (n ~ 4096 avg; guarded)
    int ni = 0;
    for (int i = tid; i < n; i += 256, ++ni) {
        int2 ed = bin[s + i];
        if (ni < 16) eds[ni] = ed;
        atomicAdd(&cnt[(ed.x >> 18) & 255], 1);
    }
    __syncthreads();
    if (tid == 0) {
        int run = 0;
#pragma unroll
        for (int r = 0; r < BROWS; ++r) { pref[r] = run; run += cnt[r]; }
    }
    __syncthreads();
    fill[tid] = pref[tid];
    __syncthreads();
    ni = 0;
    for (int i = tid; i < n; i += 256, ++ni) {
        int2 ed = (ni < 16) ? eds[ni] : bin[s + i];
        int p = atomicAdd(&fill[(ed.x >> 18) & 255], 1);
        bout[s + p] = make_int2(ed.x & 0x3ffff, ed.y);
    }
    row_start[b * BROWS + tid] = s + pref[tid];
    if (b == NB - 1 && tid == 0) row_start[M_ROWS] = e;
}

// ---------------- small converts ----------------

__global__ void xconv_kernel(const float* __restrict__ x, ushort* __restrict__ xb) {
    int i = blockIdx.x * 256 + threadIdx.x;
    __hip_bfloat16 v = __float2bfloat16(x[i]);
    xb[i] = *(ushort*)&v;
}

// Wcat[n][kkc], kkc in [0,KCAT): kkc<64 -> sum_a W[0][a*64+kkc][n] (x@Wsum term);
// else k=(kkc-64)/512+1, kk=(kkc-64)%512 -> W[k][kk][n].
__global__ void wcat_kernel(const float* __restrict__ W, ushort* __restrict__ Wcat) {
    int idx = blockIdx.x * 256 + threadIdx.x;    // 64*KCAT = 233472
    int n   = idx / KCAT;
    int kkc = idx - n * KCAT;
    float v;
    if (kkc < 64) {
        v = 0.f;
#pragma unroll
        for (int a = 0; a < NANG; ++a) v += W[(a * 64 + kkc) * 64 + n];
    } else {
        int k  = ((kkc - 64) >> 9) + 1;
        int kk = (kkc - 64) & 511;
        v = W[(size_t)k * WK_STRIDE + kk * 64 + n];
    }
    __hip_bfloat16 b = __float2bfloat16(v);
    Wcat[idx] = *(ushort*)&b;
}

// ---------------- SpMM: row-per-wave gather, readlane edge broadcast (MLP=16) ----------------
// TIN_TILED: Tin is xb [N,64], col % N_NODES. TSUB_MODE: 0 none, 1 [M,64], 2 xb tiled.

template <int TIN_TILED, int TSUB_MODE>
__global__ __launch_bounds__(256) void spmm_kernel(
        const int* __restrict__ row_start, const int2* __restrict__ edges,
        const ushort* __restrict__ Tin, const ushort* __restrict__ Tsub,
        ushort* __restrict__ Tout, float alpha, float beta) {
    int r = (blockIdx.x * 256 + threadIdx.x) >> 6;
    int lane = threadIdx.x & 63;
    if (r >= M_ROWS) return;
    int s = row_start[r];
    int e = row_start[r + 1];
    float acc = 0.f;
    for (int base = s; base < e; base += 16) {
        int idx = min(base + (lane & 15), e - 1);
        int2 ed = edges[idx];                 // 16 edges, 128B coalesced (4x dup)
#pragma unroll
        for (int i = 0; i < 16; ++i) {
            int   col = __builtin_amdgcn_readlane(ed.x, i);
            float w   = __int_as_float(__builtin_amdgcn_readlane(ed.y, i));
            if (base + i >= e) w = 0.f;       // clamped dup edge contributes 0
            unsigned c = (unsigned)col;
            if (TIN_TILED) c %= N_NODES;
            float t = bf2f(Tin[(size_t)c * CH + lane]);
            acc = fmaf(w, t, acc);
        }
    }
    size_t oi = (size_t)r * CH + lane;
    float v = alpha * acc;
    if (TSUB_MODE == 1) v += beta * bf2f(Tsub[oi]);
    if (TSUB_MODE == 2) v += beta * bf2f(Tsub[(size_t)((unsigned)r % N_NODES) * CH + lane]);
    __hip_bfloat16 o = __float2bfloat16(v);
    Tout[oi] = *(ushort*)&o;
}

// ---------------- single concatenated GEMM: out = [x | feat(T1..T7)] @ Wcat + bias --------
// One wave per block, 16 rows x 64 cols, K=3648 in 114 steps of 32.
// A layout: m=lane&15, k=(lane>>4)*8+j. C/D: col=lane&15, row=(lane>>4)*4+reg [m89].

__global__ __launch_bounds__(64) void gemm_cat_kernel(
        const ushort* __restrict__ xb,    // [N,64]
        const ushort* __restrict__ Tall,  // [7][NANG*N,64]
        const ushort* __restrict__ Wcat,  // [64][KCAT]
        const float* __restrict__ bias,
        float* __restrict__ out) {        // [N,64] fp32
    int m0 = blockIdx.x * 16;
    int l = threadIdx.x;
    int lm = l & 15;
    int lq = l >> 4;
    const short* Xp = (const short*)xb;
    const short* Tp = (const short*)Tall;
    const short* Wp = (const short*)Wcat;

    f32x4 acc[4];
#pragma unroll
    for (int t = 0; t < 4; ++t) acc[t] = (f32x4){0.f, 0.f, 0.f, 0.f};

    // s = 0,1: x @ Wsum block
#pragma unroll
    for (int s = 0; s < 2; ++s) {
        short8 af = *(const short8*)(Xp + (size_t)(m0 + lm) * CH + s * 32 + lq * 8);
#pragma unroll
        for (int t = 0; t < 4; ++t) {
            short8 bf = *(const short8*)(Wp + (size_t)(t * 16 + lm) * KCAT + s * 32 + lq * 8);
            acc[t] = __builtin_amdgcn_mfma_f32_16x16x32_bf16(af, bf, acc[t], 0, 0, 0);
        }
    }
    // s = 2..113: T segments (7 x 16 ksteps)
    for (int seg = 0; seg < 7; ++seg) {
        const short* Ts = Tp + (size_t)seg * M_ROWS * CH;
#pragma unroll
        for (int ks = 0; ks < 16; ++ks) {
            int a = ks >> 1, half = ks & 1;
            short8 af = *(const short8*)(Ts + ((size_t)(a * N_NODES + m0 + lm)) * CH + half * 32 + lq * 8);
            int scat = 2 + seg * 16 + ks;
#pragma unroll
            for (int t = 0; t < 4; ++t) {
                short8 bf = *(const short8*)(Wp + (size_t)(t * 16 + lm) * KCAT + scat * 32 + lq * 8);
                acc[t] = __builtin_amdgcn_mfma_f32_16x16x32_bf16(af, bf, acc[t], 0, 0, 0);
            }
        }
    }

#pragma unroll
    for (int t = 0; t < 4; ++t) {
        int col = t * 16 + lm;
#pragma unroll
        for (int rI = 0; rI < 4; ++rI) {
            out[(size_t)(m0 + lq * 4 + rI) * CH + col] = acc[t][rI] + bias[col];
        }
    }
}

// ---------------- launch ----------------

extern "C" void kernel_launch(void* const* d_in, const int* in_sizes, int n_in,
                              void* d_out, int out_size, void* d_ws, size_t ws_size,
                              hipStream_t stream) {
    (void)in_sizes; (void)n_in; (void)out_size; (void)ws_size;
    const float* x       = (const float*)d_in[0];
    const float* ls_vals = (const float*)d_in[1];
    const float* weight  = (const float*)d_in[2];
    const float* bias    = (const float*)d_in[3];
    const int*   ls_rows = (const int*)d_in[4];
    const int*   ls_cols = (const int*)d_in[5];
    float* out = (float*)d_out;

    char* ws = (char*)d_ws;
    size_t off = 0;
    auto alloc = [&](size_t bytes) -> void* {
        void* p = ws + off;
        off += (bytes + 255) & ~(size_t)255;
        return p;
    };
    int*  chunk_cnt = (int*)alloc((size_t)NCHUNK * NB * sizeof(int));
    int*  btotal    = (int*)alloc(NB * sizeof(int));
    int*  bstart    = (int*)alloc((NB + 1) * sizeof(int));
    int*  row_start = (int*)alloc((M_ROWS + 1) * sizeof(int));
    int2* bedges2   = (int2*)alloc((size_t)E_EDGES * sizeof(int2));
    ushort* Wcat = (ushort*)alloc((size_t)64 * KCAT * sizeof(ushort));
    ushort* xb   = (ushort*)alloc((size_t)N_NODES * CH * sizeof(ushort));
    ushort* Tall = (ushort*)alloc((size_t)7 * M_ROWS * CH * sizeof(ushort));
    // Alias: phase-1 bucket staging lives in Tall seg0 (20.48 MB each; seg0 is
    // first written by spmm#1, which runs after bucket_group has consumed bedges).
    int2* bedges = (int2*)Tall;

    // deterministic bucket build + per-bucket row grouping
    count_kernel<<<NCHUNK, 256, 0, stream>>>(ls_rows, chunk_cnt);
    btotal_kernel<<<(NB + 255) / 256, 256, 0, stream>>>(chunk_cnt, btotal);
    bscan_kernel<<<1, 1024, 0, stream>>>(btotal, bstart);
    offs_kernel<<<(NB + 255) / 256, 256, 0, stream>>>(chunk_cnt, bstart);
    scatter_kernel<<<NCHUNK, 256, 0, stream>>>(ls_rows, ls_cols, ls_vals, chunk_cnt, bedges);
    bucket_group_kernel<<<NB, 256, 0, stream>>>(bstart, bedges, bedges2, row_start);

    // converts
    xconv_kernel<<<(N_NODES * CH) / 256, 256, 0, stream>>>(x, xb);
    wcat_kernel<<<(64 * KCAT) / 256, 256, 0, stream>>>(weight, Wcat);

    ushort* T[8];  // T[k] = seg k-1
    for (int k = 1; k < K_CHEB; ++k) T[k] = Tall + (size_t)(k - 1) * M_ROWS * CH;

    // Chebyshev chain (T1 = L tile(x); Tk = 2 L T_{k-1} - T_{k-2})
    spmm_kernel<1, 0><<<SPMM_BLOCKS, 256, 0, stream>>>(
        row_start, bedges2, xb, xb, T[1], 1.f, 0.f);
    spmm_kernel<0, 2><<<SPMM_BLOCKS, 256, 0, stream>>>(
        row_start, bedges2, T[1], xb, T[2], 2.f, -1.f);
    for (int k = 3; k < K_CHEB; ++k) {
        spmm_kernel<0, 1><<<SPMM_BLOCKS, 256, 0, stream>>>(
            row_start, bedges2, T[k - 1], T[k - 2], T[k], 2.f, -1.f);
    }

    // one concatenated GEMM for all k terms
    gemm_cat_kernel<<<N_NODES / 16, 64, 0, stream>>>(xb, Tall, Wcat, bias, out);
}

// Round 10
// 737.920 us; speedup vs baseline: 1.1906x; 1.0500x over previous
//
#include <hip/hip_runtime.h>
#include <hip/hip_bf16.h>

// Problem constants (from setup_inputs)
#define N_NODES 20000
#define NANG 8
#define CH 64                      // in_size == out_size == 64
#define M_ROWS (NANG * N_NODES)    // 160000
#define E_EDGES (M_ROWS * 16)      // 2560000
#define K_CHEB 8
#define WK_STRIDE (NANG * CH * CH) // 32768 floats per weight[k]
#define BROWS 256                  // rows per bucket (good scatter write-combining)
#define NB (M_ROWS / BROWS)        // 625 buckets
#define NCHUNK 320
#define CHUNK (E_EDGES / NCHUNK)   // 8000
#define SPMM_BLOCKS (M_ROWS / 4)   // 40000
#define KCAT 3648                  // 64 (x@Wsum) + 7*512 (feat(Tk)@Wk)
#define SK_TOTAL 114               // KCAT/32 ksteps
#define BCAP 5120                  // LDS staging cap (mean 4096, sd 64 -> 16 sigma)

typedef short short8 __attribute__((ext_vector_type(8)));
typedef float f32x4 __attribute__((ext_vector_type(4)));

__device__ __forceinline__ float bf2f(ushort u) {
    return __uint_as_float((unsigned int)u << 16);
}

// ---------------- deterministic bucket build (no global atomics) ----------------

__global__ __launch_bounds__(256) void count_kernel(const int* __restrict__ rows,
                                                    int* __restrict__ chunk_cnt) {
    __shared__ int h[NB];
    int c = blockIdx.x, tid = threadIdx.x;
    for (int i = tid; i < NB; i += 256) h[i] = 0;
    __syncthreads();
    int base = c * CHUNK;
    for (int i = tid; i < CHUNK; i += 256) atomicAdd(&h[rows[base + i] >> 8], 1);
    __syncthreads();
    for (int i = tid; i < NB; i += 256) chunk_cnt[(size_t)c * NB + i] = h[i];
}

__global__ void btotal_kernel(const int* __restrict__ chunk_cnt, int* __restrict__ btotal) {
    int b = blockIdx.x * 256 + threadIdx.x;
    if (b >= NB) return;
    int s = 0;
    for (int c = 0; c < NCHUNK; ++c) s += chunk_cnt[(size_t)c * NB + b];
    btotal[b] = s;
}

// single-block exclusive scan over NB bucket totals (NB=625 <= 1024)
__global__ void bscan_kernel(const int* __restrict__ btotal, int* __restrict__ bstart) {
    __shared__ int s[1024];
    int t = threadIdx.x;
    int v = (t < NB) ? btotal[t] : 0;
    s[t] = v;
    __syncthreads();
    for (int off = 1; off < 1024; off <<= 1) {
        int u = (t >= off) ? s[t - off] : 0;
        __syncthreads();
        s[t] += u;
        __syncthreads();
    }
    if (t < NB) bstart[t] = s[t] - v;
    if (t == 1023) bstart[NB] = s[1023];
}

// chunk_cnt -> per-(chunk,bucket) write offsets, in place
__global__ void offs_kernel(int* __restrict__ chunk_cnt, const int* __restrict__ bstart) {
    int b = blockIdx.x * 256 + threadIdx.x;
    if (b >= NB) return;
    int run = bstart[b];
    for (int c = 0; c < NCHUNK; ++c) {
        int v = chunk_cnt[(size_t)c * NB + b];
        chunk_cnt[(size_t)c * NB + b] = run;
        run += v;
    }
}

// scatter into bucket-ordered streams (LDS-local offsets, sequential per-bucket writes)
__global__ __launch_bounds__(256) void scatter_kernel(
        const int* __restrict__ rows, const int* __restrict__ cols,
        const float* __restrict__ vals, const int* __restrict__ chunk_cnt,
        int2* __restrict__ bedges) {
    __shared__ int loff[NB];
    int c = blockIdx.x, tid = threadIdx.x;
    for (int i = tid; i < NB; i += 256) loff[i] = chunk_cnt[(size_t)c * NB + i];
    __syncthreads();
    int base = c * CHUNK;
    for (int i = tid; i < CHUNK; i += 256) {
        int e = base + i;
        int r = rows[e];
        int p = atomicAdd(&loff[r >> 8], 1);
        bedges[p] = make_int2(cols[e] | ((r & 255) << 18), __float_as_int(vals[e]));
    }
}

// per-bucket: group edges by row via LDS staging, then write bout SEQUENTIALLY
// (coalesced; avoids random-8B write amplification). Parallel scan for prefix.
__global__ __launch_bounds__(256) void bucket_group_kernel(
        const int* __restrict__ bstart, const int2* __restrict__ bin,
        int2* __restrict__ bout, int* __restrict__ row_start) {
    __shared__ int cnt[BROWS];
    __shared__ int pref[BROWS];
    __shared__ int fill[BROWS];
    __shared__ int2 ob[BCAP];          // 40 KB staging
    int b = blockIdx.x, tid = threadIdx.x;
    int s = bstart[b], e = bstart[b + 1];
    int n = e - s;
    cnt[tid] = 0;
    __syncthreads();
    int2 eds[20];                      // reg cache (n/256 <= 20 when n <= BCAP)
    int ni = 0;
    for (int i = tid; i < n; i += 256, ++ni) {
        int2 ed = bin[s + i];
        if (ni < 20) eds[ni] = ed;
        atomicAdd(&cnt[(ed.x >> 18) & 255], 1);
    }
    __syncthreads();
    // Hillis-Steele inclusive scan over 256 counters -> exclusive pref
    int v = cnt[tid];
    pref[tid] = v;
    __syncthreads();
#pragma unroll
    for (int off = 1; off < 256; off <<= 1) {
        int u = (tid >= off) ? pref[tid - off] : 0;
        __syncthreads();
        pref[tid] += u;
        __syncthreads();
    }
    int my_excl = pref[tid] - v;
    __syncthreads();
    pref[tid] = my_excl;
    fill[tid] = my_excl;
    __syncthreads();

    if (n <= BCAP) {
        ni = 0;
        for (int i = tid; i < n; i += 256, ++ni) {
            int2 ed = (ni < 20) ? eds[ni] : bin[s + i];
            int p = atomicAdd(&fill[(ed.x >> 18) & 255], 1);
            ob[p] = make_int2(ed.x & 0x3ffff, ed.y);
        }
        __syncthreads();
        for (int i = tid; i < n; i += 256)
            bout[s + i] = ob[i];       // sequential, coalesced
    } else {
        // fallback (statistically unreachable): direct global scatter
        ni = 0;
        for (int i = tid; i < n; i += 256, ++ni) {
            int2 ed = (ni < 20) ? eds[ni] : bin[s + i];
            int p = atomicAdd(&fill[(ed.x >> 18) & 255], 1);
            bout[s + p] = make_int2(ed.x & 0x3ffff, ed.y);
        }
    }
    row_start[b * BROWS + tid] = s + pref[tid];
    if (b == NB - 1 && tid == 0) row_start[M_ROWS] = e;
}

// ---------------- small converts ----------------

__global__ void xconv_kernel(const float* __restrict__ x, ushort* __restrict__ xb) {
    int i = blockIdx.x * 256 + threadIdx.x;
    __hip_bfloat16 v = __float2bfloat16(x[i]);
    xb[i] = *(ushort*)&v;
}

// Wcat[n][kkc], kkc in [0,KCAT): kkc<64 -> sum_a W[0][a*64+kkc][n] (x@Wsum term);
// else k=(kkc-64)/512+1, kk=(kkc-64)%512 -> W[k][kk][n].
__global__ void wcat_kernel(const float* __restrict__ W, ushort* __restrict__ Wcat) {
    int idx = blockIdx.x * 256 + threadIdx.x;    // 64*KCAT = 233472
    int n   = idx / KCAT;
    int kkc = idx - n * KCAT;
    float v;
    if (kkc < 64) {
        v = 0.f;
#pragma unroll
        for (int a = 0; a < NANG; ++a) v += W[(a * 64 + kkc) * 64 + n];
    } else {
        int k  = ((kkc - 64) >> 9) + 1;
        int kk = (kkc - 64) & 511;
        v = W[(size_t)k * WK_STRIDE + kk * 64 + n];
    }
    __hip_bfloat16 b = __float2bfloat16(v);
    Wcat[idx] = *(ushort*)&b;
}

// ---------------- SpMM: row-per-wave gather, readlane edge broadcast (MLP=16) ----------------
// TIN_TILED: Tin is xb [N,64], col % N_NODES. TSUB_MODE: 0 none, 1 [M,64], 2 xb tiled.

template <int TIN_TILED, int TSUB_MODE>
__global__ __launch_bounds__(256) void spmm_kernel(
        const int* __restrict__ row_start, const int2* __restrict__ edges,
        const ushort* __restrict__ Tin, const ushort* __restrict__ Tsub,
        ushort* __restrict__ Tout, float alpha, float beta) {
    int r = (blockIdx.x * 256 + threadIdx.x) >> 6;
    int lane = threadIdx.x & 63;
    if (r >= M_ROWS) return;
    int s = row_start[r];
    int e = row_start[r + 1];
    float acc = 0.f;
    for (int base = s; base < e; base += 16) {
        int idx = min(base + (lane & 15), e - 1);
        int2 ed = edges[idx];                 // 16 edges, 128B coalesced (4x dup)
#pragma unroll
        for (int i = 0; i < 16; ++i) {
            int   col = __builtin_amdgcn_readlane(ed.x, i);
            float w   = __int_as_float(__builtin_amdgcn_readlane(ed.y, i));
            if (base + i >= e) w = 0.f;       // clamped dup edge contributes 0
            unsigned c = (unsigned)col;
            if (TIN_TILED) c %= N_NODES;
            float t = bf2f(Tin[(size_t)c * CH + lane]);
            acc = fmaf(w, t, acc);
        }
    }
    size_t oi = (size_t)r * CH + lane;
    float v = alpha * acc;
    if (TSUB_MODE == 1) v += beta * bf2f(Tsub[oi]);
    if (TSUB_MODE == 2) v += beta * bf2f(Tsub[(size_t)((unsigned)r % N_NODES) * CH + lane]);
    __hip_bfloat16 o = __float2bfloat16(v);
    Tout[oi] = *(ushort*)&o;
}

// ---------------- concatenated GEMM, K-split: out = [x | feat(T1..T7)] @ Wcat + bias ----
// 256 threads = 4 waves per 16-row tile; wave w handles ksteps [29w, 29w+29) of 114,
// then LDS reduction. 5000 waves total (~20/CU) to hide A-load latency.
// A layout: m=lane&15, k=(lane>>4)*8+j. C/D: col=lane&15, row=(lane>>4)*4+reg [m89].

__global__ __launch_bounds__(256) void gemm_cat_kernel(
        const ushort* __restrict__ xb,    // [N,64]
        const ushort* __restrict__ Tall,  // [7][NANG*N,64]
        const ushort* __restrict__ Wcat,  // [64][KCAT]
        const float* __restrict__ bias,
        float* __restrict__ out) {        // [N,64] fp32
    __shared__ float red[4][65][16];      // w-stride 65*16 floats -> 2-way bank alias (free)
    int m0 = blockIdx.x * 16;
    int w = threadIdx.x >> 6;
    int l = threadIdx.x & 63;
    int lm = l & 15;
    int lq = l >> 4;
    const short* Xp = (const short*)xb;
    const short* Tp = (const short*)Tall;
    const short* Wp = (const short*)Wcat;

    f32x4 acc[4];
#pragma unroll
    for (int t = 0; t < 4; ++t) acc[t] = (f32x4){0.f, 0.f, 0.f, 0.f};

    int sk0 = w * 29;
    int sk1 = min(sk0 + 29, SK_TOTAL);
    for (int sk = sk0; sk < sk1; ++sk) {
        short8 af;
        if (sk < 2) {
            af = *(const short8*)(Xp + (size_t)(m0 + lm) * CH + sk * 32 + lq * 8);
        } else {
            int seg = (sk - 2) >> 4;
            int ks  = (sk - 2) & 15;
            int a = ks >> 1, half = ks & 1;
            af = *(const short8*)(Tp + (size_t)seg * M_ROWS * CH
                                  + ((size_t)(a * N_NODES + m0 + lm)) * CH + half * 32 + lq * 8);
        }
#pragma unroll
        for (int t = 0; t < 4; ++t) {
            short8 bf = *(const short8*)(Wp + (size_t)(t * 16 + lm) * KCAT + sk * 32 + lq * 8);
            acc[t] = __builtin_amdgcn_mfma_f32_16x16x32_bf16(af, bf, acc[t], 0, 0, 0);
        }
    }

#pragma unroll
    for (int t = 0; t < 4; ++t)
#pragma unroll
        for (int rI = 0; rI < 4; ++rI) red[w][l][t * 4 + rI] = acc[t][rI];
    __syncthreads();
    if (w == 0) {
#pragma unroll
        for (int t = 0; t < 4; ++t) {
            int col = t * 16 + lm;
#pragma unroll
            for (int rI = 0; rI < 4; ++rI) {
                int i = t * 4 + rI;
                float sum = red[0][l][i] + red[1][l][i] + red[2][l][i] + red[3][l][i];
                out[(size_t)(m0 + lq * 4 + rI) * CH + col] = sum + bias[col];
            }
        }
    }
}

// ---------------- launch ----------------

extern "C" void kernel_launch(void* const* d_in, const int* in_sizes, int n_in,
                              void* d_out, int out_size, void* d_ws, size_t ws_size,
                              hipStream_t stream) {
    (void)in_sizes; (void)n_in; (void)out_size; (void)ws_size;
    const float* x       = (const float*)d_in[0];
    const float* ls_vals = (const float*)d_in[1];
    const float* weight  = (const float*)d_in[2];
    const float* bias    = (const float*)d_in[3];
    const int*   ls_rows = (const int*)d_in[4];
    const int*   ls_cols = (const int*)d_in[5];
    float* out = (float*)d_out;

    char* ws = (char*)d_ws;
    size_t off = 0;
    auto alloc = [&](size_t bytes) -> void* {
        void* p = ws + off;
        off += (bytes + 255) & ~(size_t)255;
        return p;
    };
    int*  chunk_cnt = (int*)alloc((size_t)NCHUNK * NB * sizeof(int));
    int*  btotal    = (int*)alloc(NB * sizeof(int));
    int*  bstart    = (int*)alloc((NB + 1) * sizeof(int));
    int*  row_start = (int*)alloc((M_ROWS + 1) * sizeof(int));
    int2* bedges2   = (int2*)alloc((size_t)E_EDGES * sizeof(int2));
    ushort* Wcat = (ushort*)alloc((size_t)64 * KCAT * sizeof(ushort));
    ushort* xb   = (ushort*)alloc((size_t)N_NODES * CH * sizeof(ushort));
    ushort* Tall = (ushort*)alloc((size_t)7 * M_ROWS * CH * sizeof(ushort));
    // Alias: phase-1 bucket staging lives in Tall seg0 (20.48 MB each; seg0 is
    // first written by spmm#1, which runs after bucket_group has consumed bedges).
    int2* bedges = (int2*)Tall;

    // deterministic bucket build + per-bucket row grouping
    count_kernel<<<NCHUNK, 256, 0, stream>>>(ls_rows, chunk_cnt);
    btotal_kernel<<<(NB + 255) / 256, 256, 0, stream>>>(chunk_cnt, btotal);
    bscan_kernel<<<1, 1024, 0, stream>>>(btotal, bstart);
    offs_kernel<<<(NB + 255) / 256, 256, 0, stream>>>(chunk_cnt, bstart);
    scatter_kernel<<<NCHUNK, 256, 0, stream>>>(ls_rows, ls_cols, ls_vals, chunk_cnt, bedges);
    bucket_group_kernel<<<NB, 256, 0, stream>>>(bstart, bedges, bedges2, row_start);

    // converts
    xconv_kernel<<<(N_NODES * CH) / 256, 256, 0, stream>>>(x, xb);
    wcat_kernel<<<(64 * KCAT) / 256, 256, 0, stream>>>(weight, Wcat);

    ushort* T[8];  // T[k] = seg k-1
    for (int k = 1; k < K_CHEB; ++k) T[k] = Tall + (size_t)(k - 1) * M_ROWS * CH;

    // Chebyshev chain (T1 = L tile(x); Tk = 2 L T_{k-1} - T_{k-2})
    spmm_kernel<1, 0><<<SPMM_BLOCKS, 256, 0, stream>>>(
        row_start, bedges2, xb, xb, T[1], 1.f, 0.f);
    spmm_kernel<0, 2><<<SPMM_BLOCKS, 256, 0, stream>>>(
        row_start, bedges2, T[1], xb, T[2], 2.f, -1.f);
    for (int k = 3; k < K_CHEB; ++k) {
        spmm_kernel<0, 1><<<SPMM_BLOCKS, 256, 0, stream>>>(
            row_start, bedges2, T[k - 1], T[k - 2], T[k], 2.f, -1.f);
    }

    // one concatenated GEMM for all k terms
    gemm_cat_kernel<<<N_NODES / 16, 256, 0, stream>>>(xb, Tall, Wcat, bias, out);
}